// Round 14
// baseline (130.423 us; speedup 1.0000x reference)
//
#include <hip/hip_runtime.h>
#include <math.h>

#define OS    320      // oversampled grid (ceil(1.25*256))
#define IMN   256
#define NCOIL 8
#define HS    326      // halo grid dim (3-cell wrap halo each side)
#define HROWB (HS * 32)   // halo row stride in bytes (cell = 32B)
#define PI_F  3.14159265358979f
#define BETA_F 10.955108f   // pi*sqrt((4.8*0.75)^2 - 0.8)
#define GSCALE 65536.0f     // fp16 grid scaling

typedef _Float16 half4  __attribute__((ext_vector_type(4)));
typedef unsigned uint2v __attribute__((ext_vector_type(2)));

// f32 acc += f32 w * f16 (lo/hi half of dword h)   [validated r6/r8]
__device__ __forceinline__ void fmamix_lo(float& acc, float w, unsigned h) {
    asm("v_fma_mix_f32 %0, %1, %2, %0 op_sel_hi:[0,1,0]"
        : "+v"(acc) : "v"(w), "v"(h));
}
__device__ __forceinline__ void fmamix_hi(float& acc, float w, unsigned h) {
    asm("v_fma_mix_f32 %0, %1, %2, %0 op_sel:[0,1,0] op_sel_hi:[0,1,0]"
        : "+v"(acc) : "v"(w), "v"(h));
}

// ---- Kaiser-Bessel: exact A&S I0 polynomial (matches reference) ----
__device__ __forceinline__ float i0f(float x) {
    if (x < 3.75f) {
        float y = x * (1.0f / 3.75f); y *= y;
        return 1.0f + y*(3.5156229f + y*(3.0899424f + y*(1.2067492f
             + y*(0.2659732f + y*(0.0360768f + y*0.0045813f)))));
    } else {
        float t = 3.75f / x;
        float p = 0.39894228f + t*(0.01328592f + t*(0.00225319f + t*(-0.00157565f
              + t*(0.00916281f + t*(-0.02057706f + t*(0.02635537f + t*(-0.01647633f
              + t*0.00392377f)))))));
        return expf(x) * rsqrtf(x) * p;
    }
}

__device__ __forceinline__ float apod1(int i) {
    float idx = (float)(i - 128);
    float c = PI_F * 6.0f * idx * (1.0f / (float)OS);
    float a = sqrtf(BETA_F * BETA_F - c * c);
    float sh = 0.5f * (expf(a) - expf(-a));
    return a / sh;
}

// ======== FFT core: 320 = 5 x 64 (validated r12) ========
#define FFT_STAGES(lds, tw64, cc, bb, jj)                                   \
  {                                                                         \
    int base_ = ((cc) * 5 + (bb)) * 65;                                     \
    _Pragma("unroll")                                                       \
    for (int s_ = 0; s_ < 6; ++s_) {                                        \
      int h_ = 32 >> s_;                                                    \
      int i_ = (jj) & (h_ - 1);                                             \
      int p_ = (((jj) >> (5 - s_)) << (6 - s_)) + i_;                       \
      float2 u_ = lds[base_ + p_];                                          \
      float2 v_ = lds[base_ + p_ + h_];                                     \
      float2 w_ = tw64[i_ << s_];                                           \
      lds[base_ + p_] = make_float2(u_.x + v_.x, u_.y + v_.y);              \
      float dx_ = u_.x - v_.x, dy_ = u_.y - v_.y;                           \
      lds[base_ + p_ + h_] =                                                \
          make_float2(dx_ * w_.x - dy_ * w_.y, dx_ * w_.y + dy_ * w_.x);    \
      __syncthreads();                                                      \
    }                                                                       \
  }

// ---- K1: fused apod + pad + FFT along x (validated r12); also builds the
// interp weight LUT in its first 4 y==0 blocks (saves a launch).
__global__ __launch_bounds__(320) void fft_pass1(const float* __restrict__ imr,
                                                 const float* __restrict__ imi,
                                                 float2* __restrict__ out,
                                                 float* __restrict__ lut) {
    __shared__ float2 xg[10 * 65];
    __shared__ float2 tw64[33];
    int iy = blockIdx.x;
    int c0 = blockIdx.y * 2;
    int t  = threadIdx.x;

    if (blockIdx.y == 0 && blockIdx.x < 4) {   // LUT fold: 4x320 >= 1025
        int i = blockIdx.x * 320 + t;
        if (i <= 1024)
            lut[i] = i0f(BETA_F * sqrtf(1.0f - (float)i * (1.0f / 1024.0f)));
    }
    if (t < 33) {
        float ang = (float)t * (-2.0f * PI_F / 64.0f);
        tw64[t] = make_float2(cosf(ang), sinf(ang));
    }
    for (int s = t; s < 640; s += 320) {
        int c = (s >= 320) ? 1 : 0;
        int n = s - c * 320;
        int b = n % 5, a = n / 5;
        float2 v = make_float2(0.f, 0.f);
        if (n >= 192 || n < 128) {
            int ix = (n >= 192) ? (n - 192) : (n + 128);
            float ap = apod1(ix);
            int gi = (c0 + c) * (IMN * IMN) + iy * IMN + ix;
            v = make_float2(imr[gi] * ap, imi[gi] * ap);
        }
        xg[(c * 5 + b) * 65 + a] = v;
    }
    __syncthreads();

    {
        int c = t / 160, r = t - c * 160;
        int b = r >> 5, j = r & 31;
        FFT_STAGES(xg, tw64, c, b, j)
    }

    int k = t;
    int rm = __brev((unsigned)(k & 63)) >> 26;
    float ang1 = (float)k * (-2.0f * PI_F / 320.0f);
    float w1r = cosf(ang1), w1i = sinf(ang1);
    float w2r = w1r * w1r - w1i * w1i, w2i = 2.0f * w1r * w1i;
    float w3r = w2r * w1r - w2i * w1i, w3i = w2r * w1i + w2i * w1r;
    float w4r = w2r * w2r - w2i * w2i, w4i = 2.0f * w2r * w2i;
    float ay = apod1(iy) * (1.0f / 256.0f);
    int y = iy + 192; if (y >= OS) y -= OS;
    float Fr[2], Fi[2];
    #pragma unroll
    for (int c = 0; c < 2; ++c) {
        int base = c * 5 * 65;
        float2 g0 = xg[base + rm];
        float2 g1 = xg[base + 65 + rm];
        float2 g2 = xg[base + 130 + rm];
        float2 g3 = xg[base + 195 + rm];
        float2 g4 = xg[base + 260 + rm];
        float fr = g0.x, fi = g0.y;
        fr += g1.x * w1r - g1.y * w1i;  fi += g1.x * w1i + g1.y * w1r;
        fr += g2.x * w2r - g2.y * w2i;  fi += g2.x * w2i + g2.y * w2r;
        fr += g3.x * w3r - g3.y * w3i;  fi += g3.x * w3i + g3.y * w3r;
        fr += g4.x * w4r - g4.y * w4i;  fi += g4.x * w4i + g4.y * w4r;
        Fr[c] = fr * ay; Fi[c] = fi * ay;
    }
    *(float4*)(out + ((size_t)k * OS + y) * NCOIL + c0) =
        make_float4(Fr[0], Fi[0], Fr[1], Fi[1]);
}

// ---- K2: FFT along y; fp16 HALO grid out, fftshift folded (validated r12) ----
__global__ __launch_bounds__(320) void fft_pass2(const float2* __restrict__ in,
                                                 char* __restrict__ gbytes) {
    __shared__ float2 xg[10 * 65];
    __shared__ float2 tw64[33];
    int kx = blockIdx.x;
    int c0 = blockIdx.y * 2;
    int t  = threadIdx.x;

    if (t < 33) {
        float ang = (float)t * (-2.0f * PI_F / 64.0f);
        tw64[t] = make_float2(cosf(ang), sinf(ang));
    }
    const float2* row = in + (size_t)kx * OS * NCOIL + c0;
    for (int s = t; s < 640; s += 320) {
        int c = (s >= 320) ? 1 : 0;
        int n = s - c * 320;
        int b = n % 5, a = n / 5;
        float2 v = make_float2(0.f, 0.f);
        if (n >= 192 || n < 128)
            v = row[n * NCOIL + c];
        xg[(c * 5 + b) * 65 + a] = v;
    }
    __syncthreads();

    {
        int c = t / 160, r = t - c * 160;
        int b = r >> 5, j = r & 31;
        FFT_STAGES(xg, tw64, c, b, j)
    }

    int k = t;
    int rm = __brev((unsigned)(k & 63)) >> 26;
    float ang1 = (float)k * (-2.0f * PI_F / 320.0f);
    float w1r = cosf(ang1), w1i = sinf(ang1);
    float w2r = w1r * w1r - w1i * w1i, w2i = 2.0f * w1r * w1i;
    float w3r = w2r * w1r - w2i * w1i, w3i = w2r * w1i + w2i * w1r;
    float w4r = w2r * w2r - w2i * w2i, w4i = 2.0f * w2r * w2i;
    float Fr[2], Fi[2];
    #pragma unroll
    for (int c = 0; c < 2; ++c) {
        int base = c * 5 * 65;
        float2 g0 = xg[base + rm];
        float2 g1 = xg[base + 65 + rm];
        float2 g2 = xg[base + 130 + rm];
        float2 g3 = xg[base + 195 + rm];
        float2 g4 = xg[base + 260 + rm];
        float fr = g0.x, fi = g0.y;
        fr += g1.x * w1r - g1.y * w1i;  fi += g1.x * w1i + g1.y * w1r;
        fr += g2.x * w2r - g2.y * w2i;  fi += g2.x * w2i + g2.y * w2r;
        fr += g3.x * w3r - g3.y * w3i;  fi += g3.x * w3i + g3.y * w3r;
        fr += g4.x * w4r - g4.y * w4i;  fi += g4.x * w4i + g4.y * w4r;
        Fr[c] = fr * GSCALE; Fi[c] = fi * GSCALE;
    }
    int r = k + 160;  if (r >= OS) r -= OS;
    int c2 = kx + 160; if (c2 >= OS) c2 -= OS;
    half4 hh;
    hh[0] = (_Float16)Fr[0]; hh[1] = (_Float16)Fi[0];
    hh[2] = (_Float16)Fr[1]; hh[3] = (_Float16)Fi[1];
    int hys[2]; int nhy = 1; hys[0] = r + 3;
    if (r < 3)        hys[nhy++] = r + 323;
    else if (r >= 317) hys[nhy++] = r - 317;
    int hxs[2]; int nhx = 1; hxs[0] = c2 + 3;
    if (c2 < 3)        hxs[nhx++] = c2 + 323;
    else if (c2 >= 317) hxs[nhx++] = c2 - 317;
    for (int a = 0; a < nhy; ++a)
        for (int b = 0; b < nhx; ++b)
            *(half4*)(gbytes + (size_t)hys[a] * HROWB + hxs[b] * 32 + c0 * 4) = hh;
}

// ---- K3: KB 6x6 gather, 4 lanes/point (r13 structure, fastest measured).
// trj via NT load so the 8MB stream doesn't evict the L2-resident grid.
__global__ __launch_bounds__(256) void interp_kernel(const float* __restrict__ trj,
                                                     const char* __restrict__ gbytes,
                                                     const float* __restrict__ lut,
                                                     float2* __restrict__ out, int K) {
    int tid = blockIdx.x * 256 + threadIdx.x;
    int k  = tid >> 2;          // point index
    int cp = tid & 3;           // coil pair (coils 2cp, 2cp+1)
    if (k >= K) return;
    double td = __builtin_nontemporal_load((const double*)trj + k);
    union { double d; float2 f; } tu; tu.d = td;
    float2 tj = tu.f;
    float cy = tj.x * 1.25f + 160.0f;
    float cx = tj.y * 1.25f + 160.0f;
    int y0 = (int)ceilf(cy - 3.0f);
    int x0 = (int)ceilf(cx - 3.0f);
    const char* base0 = gbytes + (size_t)(y0 + 3) * HROWB + (x0 + 3) * 32 + cp * 8;

    // all 36 tap loads issued before any consumption
    half4 h[36];
    #pragma unroll
    for (int j = 0; j < 6; ++j) {
        const char* rb = base0 + j * HROWB;
        #pragma unroll
        for (int l = 0; l < 6; ++l)
            h[j * 6 + l] = *(const half4*)(rb + l * 32);
    }
    __builtin_amdgcn_sched_barrier(0);   // keep loads ahead of weight path

    // 12 weights per point from 3 LUT evals per lane, 4-lane shfl distribute
    float argA = ((float)(y0 + cp) - cy) * (1.0f / 3.0f);           // wy[cp]
    float argB = ((float)(x0 + cp) - cx) * (1.0f / 3.0f);           // wx[cp]
    float argC = (cp < 2) ? ((float)(y0 + 4 + cp) - cy) * (1.0f / 3.0f)   // wy[4+cp]
                          : ((float)(x0 + 2 + cp) - cx) * (1.0f / 3.0f);  // wx[2+cp]
    float tA = fminf(argA * argA * 1024.0f, 1023.0f);
    int   iA = (int)tA;  float fA = tA - (float)iA;
    float uA = fmaf(fA, lut[iA + 1] - lut[iA], lut[iA]);
    float tB = fminf(argB * argB * 1024.0f, 1023.0f);
    int   iB = (int)tB;  float fB = tB - (float)iB;
    float uB = fmaf(fB, lut[iB + 1] - lut[iB], lut[iB]);
    float tC = fminf(argC * argC * 1024.0f, 1023.0f);
    int   iC = (int)tC;  float fC = tC - (float)iC;
    float uC = fmaf(fC, lut[iC + 1] - lut[iC], lut[iC]);

    int gb = (threadIdx.x & 63) & 60;   // 4-lane group base within wave
    float wy[6], wx[6];
    wy[0] = __shfl(uA, gb + 0); wy[1] = __shfl(uA, gb + 1);
    wy[2] = __shfl(uA, gb + 2); wy[3] = __shfl(uA, gb + 3);
    wx[0] = __shfl(uB, gb + 0); wx[1] = __shfl(uB, gb + 1);
    wx[2] = __shfl(uB, gb + 2); wx[3] = __shfl(uB, gb + 3);
    wy[4] = __shfl(uC, gb + 0); wy[5] = __shfl(uC, gb + 1);
    wx[4] = __shfl(uC, gb + 2); wx[5] = __shfl(uC, gb + 3);

    float r0 = 0.f, i0 = 0.f, r1 = 0.f, i1 = 0.f;
    #pragma unroll
    for (int j = 0; j < 6; ++j) {
        float wyj = wy[j];
        #pragma unroll
        for (int l = 0; l < 6; ++l) {
            float w = wyj * wx[l];
            uint2v hu = __builtin_bit_cast(uint2v, h[j * 6 + l]);
            fmamix_lo(r0, w, hu.x);   // coil 2cp   re
            fmamix_hi(i0, w, hu.x);   //            im
            fmamix_lo(r1, w, hu.y);   // coil 2cp+1 re
            fmamix_hi(i1, w, hu.y);
        }
    }
    const float s = 1.0f / (36.0f * GSCALE);
    union { float2 f; double d; } u0, u1;
    u0.f = make_float2(r0 * s, i0 * s);
    u1.f = make_float2(r1 * s, i1 * s);
    __builtin_nontemporal_store(u0.d, (double*)(out + (size_t)(2 * cp) * K + k));
    __builtin_nontemporal_store(u1.d, (double*)(out + (size_t)(2 * cp + 1) * K + k));
}

extern "C" void kernel_launch(void* const* d_in, const int* in_sizes, int n_in,
                              void* d_out, int out_size, void* d_ws, size_t ws_size,
                              hipStream_t stream) {
    const float* imr = (const float*)d_in[0];
    const float* imi = (const float*)d_in[1];
    const float* trj = (const float*)d_in[2];
    int K = in_sizes[2] / 2;

    char* ws = (char*)d_ws;
    float2* buf1  = (float2*)ws;                 // [kx][y][coil]  6,553,600 B
    char*   gridh = ws + 6553600;                // halo fp16 grid 3,400,832 B
    float*  lut   = (float*)(ws + 9954432);      // 4,100 B

    (void)n_in; (void)out_size; (void)ws_size;

    fft_pass1<<<dim3(IMN, 4), 320, 0, stream>>>(imr, imi, buf1, lut);
    fft_pass2<<<dim3(OS, 4), 320, 0, stream>>>(buf1, gridh);
    interp_kernel<<<(K * 4 + 255) / 256, 256, 0, stream>>>(trj, gridh, lut,
                                                           (float2*)d_out, K);
}